// Round 5
// baseline (231.750 us; speedup 1.0000x reference)
//
#include <hip/hip_runtime.h>
#include <math.h>

#define BATCH 32
#define NPIX 160
#define CH 3
#define LDIM 128
#define OUT_SZ 150        // 160 - 11 + 1
#define P 38              // (160-12)/4 + 1

// ---------- split-path geometry ----------
#define V_BLOCKS_PER_BC 12             // 12*256 = 3072 >= 3000 (2-orow tasks)
#define H_BLOCKS_PER_BC 23             // 23*256 = 5888 >= 150*38
#define A_BLOCKS_PER_BC 24             // 24*256 = 6144 >= 160*38
#define H_TOTAL (H_BLOCKS_PER_BC*CH*BATCH)    // 2208
#define B_TOTAL (P*CH*BATCH)                  // 3648
#define SPLIT_PARTIALS (H_TOTAL + B_TOTAL)    // 5856
#define BC_STRIDE 121600               // floats per (bl,c) in shared scratch region
#define REGION_OFF 32768               // bytes reserved for partials at ws start

// ---------- fallback geometry (R4 kernels) ----------
#define SSIM_TILES 19
#define FB_SSIM_BLOCKS (SSIM_TILES*CH*BATCH)   // 1824
#define FB_STFT_PRG 19
#define FB_STFT_BLOCKS (FB_STFT_PRG*CH*BATCH)  // 1824
#define FB_PARTIALS (FB_SSIM_BLOCKS + FB_STFT_BLOCKS)
#define RSTRIDE 164

// e^{-i*2pi*k/12} (folds at compile time in unrolled loops)
__device__ constexpr float TWC[12] = { 1.f, 0.86602540f, 0.5f, 0.f, -0.5f, -0.86602540f,
                                      -1.f,-0.86602540f,-0.5f, 0.f,  0.5f,  0.86602540f};
__device__ constexpr float TWS[12] = { 0.f,-0.5f,-0.86602540f,-1.f,-0.86602540f,-0.5f,
                                       0.f, 0.5f, 0.86602540f, 1.f, 0.86602540f, 0.5f};

// normalized gaussian(11, sigma=1.5) — identical constants to passing rounds
__device__ constexpr float GW[11] = {0.00102838f, 0.00759876f, 0.03600076f, 0.10936070f,
                                     0.21300554f, 0.26601172f, 0.21300554f, 0.10936070f,
                                     0.03600076f, 0.00759876f, 0.00102838f};

template<int NWAVES>
__device__ __forceinline__ float block_sum(float v) {
    #pragma unroll
    for (int o = 32; o > 0; o >>= 1) v += __shfl_down(v, o, 64);
    __shared__ float sm[NWAVES];
    int w = threadIdx.x >> 6;
    if ((threadIdx.x & 63) == 0) sm[w] = v;
    __syncthreads();
    if (threadIdx.x == 0) {
        v = sm[0];
        #pragma unroll
        for (int i = 1; i < NWAVES; ++i) v += sm[i];
    }
    return v;
}

// ================= SPLIT PATH =================

// ---- ssimV: vertical 11-tap, 2 output rows per task, LDS-free ----
template<int C>
__device__ __forceinline__ void ssimV_body(const float* __restrict__ xin,
                                           const float* __restrict__ xout,
                                           float* __restrict__ R,
                                           int t, int bl, int bg) {
    int colq = t % 40;
    int orow0 = (t / 40) * 2;          // 0..148
    float acc[2][5][4];
    #pragma unroll
    for (int s = 0; s < 2; ++s)
        #pragma unroll
        for (int p = 0; p < 5; ++p)
            #pragma unroll
            for (int o = 0; o < 4; ++o) acc[s][p][o] = 0.f;

    #pragma unroll
    for (int r = 0; r < 12; ++r) {
        size_t wbase = ((size_t)(bg * NPIX + orow0 + r) * NPIX + colq * 4) * 3;
        const float4* qx = (const float4*)&xin[wbase];
        const float4* qy = (const float4*)&xout[wbase];
        float4 a0 = qx[0], a1 = qx[1], a2 = qx[2], a3 = qx[3];
        float4 b0 = qy[0], b1 = qy[1], b2 = qy[2], b3 = qy[3];
        float wx[16] = {a0.x,a0.y,a0.z,a0.w, a1.x,a1.y,a1.z,a1.w,
                        a2.x,a2.y,a2.z,a2.w, a3.x,a3.y,a3.z,a3.w};
        float wy[16] = {b0.x,b0.y,b0.z,b0.w, b1.x,b1.y,b1.z,b1.w,
                        b2.x,b2.y,b2.z,b2.w, b3.x,b3.y,b3.z,b3.w};
        float xv[4], yv[4];
        #pragma unroll
        for (int o = 0; o < 4; ++o) { xv[o] = wx[C + 3*o]; yv[o] = wy[C + 3*o]; }
        #pragma unroll
        for (int s = 0; s < 2; ++s) {
            int k = r - s;                       // compile-time per (r,s)
            if (k >= 0 && k <= 10) {
                float w = GW[k];
                #pragma unroll
                for (int o = 0; o < 4; ++o) {
                    float xo = xv[o], yo = yv[o];
                    acc[s][0][o] += w * xo;
                    acc[s][1][o] += w * yo;
                    acc[s][2][o] += w * (xo * xo);
                    acc[s][3][o] += w * (yo * yo);
                    acc[s][4][o] += w * (xo * yo);
                }
            }
        }
    }
    float* Rb = R + (size_t)(bl * 3 + C) * BC_STRIDE;
    #pragma unroll
    for (int s = 0; s < 2; ++s)
        #pragma unroll
        for (int p = 0; p < 5; ++p)
            *(float4*)&Rb[p * 24000 + (orow0 + s) * NPIX + colq * 4] =
                make_float4(acc[s][p][0], acc[s][p][1], acc[s][p][2], acc[s][p][3]);
}

__global__ __launch_bounds__(256) void ssimV_kernel(const float* __restrict__ xin,
                                                    const float* __restrict__ xout,
                                                    float* __restrict__ R, int b0) {
    int t = blockIdx.x * 256 + threadIdx.x;
    if (t >= 3000) return;
    int c = blockIdx.y, bl = blockIdx.z;
    int bg = b0 + bl;
    if (c == 0) ssimV_body<0>(xin, xout, R, t, bl, bg);
    else if (c == 1) ssimV_body<1>(xin, xout, R, t, bl, bg);
    else ssimV_body<2>(xin, xout, R, t, bl, bg);
}

// ---- ssimH: horizontal 11-tap + SSIM formula + reduce ----
__global__ __launch_bounds__(256) void ssimH_kernel(const float* __restrict__ R,
                                                    float* __restrict__ partial, int b0) {
    int t = blockIdx.x * 256 + threadIdx.x;
    int c = blockIdx.y, bl = blockIdx.z;
    float acc = 0.f;
    if (t < 5700) {
        int ocq = t % 38;
        int orow = t / 38;
        const float* Rb = R + (size_t)(bl * 3 + c) * BC_STRIDE;
        float st[5][4];
        #pragma unroll
        for (int p = 0; p < 5; ++p) {
            const float4* q = (const float4*)&Rb[p * 24000 + orow * NPIX + ocq * 4];
            float4 f0 = q[0], f1 = q[1], f2 = q[2], f3 = q[3];
            float vals[16] = {f0.x,f0.y,f0.z,f0.w, f1.x,f1.y,f1.z,f1.w,
                              f2.x,f2.y,f2.z,f2.w, f3.x,f3.y,f3.z,f3.w};
            #pragma unroll
            for (int o = 0; o < 4; ++o) {
                float s = 0.f;
                #pragma unroll
                for (int k = 0; k < 11; ++k) s += GW[k] * vals[o + k];
                st[p][o] = s;
            }
        }
        const float c1 = 1e-4f, c2 = 9e-4f;
        #pragma unroll
        for (int o = 0; o < 4; ++o) {
            if (ocq * 4 + o < OUT_SZ) {
                float mx = st[0][o], my = st[1][o];
                float vx = st[2][o] - mx * mx;
                float vy = st[3][o] - my * my;
                float cv = st[4][o] - mx * my;
                float lum = (2.f * mx * my + c1) / (mx * mx + my * my + c1);
                float cs  = (2.f * cv + c2) / (vx + vy + c2);
                acc += lum * cs;
            }
        }
    }
    acc *= 1.f / (32.f * 150.f * 150.f * 3.f);
    float s = block_sum<4>(acc);
    if (threadIdx.x == 0)
        partial[blockIdx.x + H_BLOCKS_PER_BC * (c + 3 * (b0 + bl))] = s;
}

// ---- stftA: row DFT once per (row, pc), LDS-free, dense 80B/lane writes ----
template<int C>
__device__ __forceinline__ void stftA_body(const float* __restrict__ src,
                                           float* __restrict__ RDb,
                                           int row, int pc, int bg, int img) {
    size_t wbase = ((size_t)(bg * NPIX + row) * NPIX + pc * 4) * 3;
    const float4* q = (const float4*)&src[wbase];
    float4 a0=q[0],a1=q[1],a2=q[2],a3=q[3],a4=q[4],a5=q[5],a6=q[6],a7=q[7],a8=q[8];
    float w36[36] = {a0.x,a0.y,a0.z,a0.w, a1.x,a1.y,a1.z,a1.w, a2.x,a2.y,a2.z,a2.w,
                     a3.x,a3.y,a3.z,a3.w, a4.x,a4.y,a4.z,a4.w, a5.x,a5.y,a5.z,a5.w,
                     a6.x,a6.y,a6.z,a6.w, a7.x,a7.y,a7.z,a7.w, a8.x,a8.y,a8.z,a8.w};
    float x[12];
    #pragma unroll
    for (int j = 0; j < 12; ++j) x[j] = w36[C + 3*j];
    float rre[5] = {0,0,0,0,0}, rim[5] = {0,0,0,0,0};
    #pragma unroll
    for (int j = 0; j < 12; ++j) {
        #pragma unroll
        for (int vv = 0; vv < 5; ++vv) {
            int k = ((vv + 1) * j) % 12;        // compile-time
            rre[vv] += x[j] * TWC[k];
            rim[vv] += x[j] * TWS[k];
        }
    }
    float* w = RDb + (size_t)row * 760 + pc * 20 + img * 2;
    #pragma unroll
    for (int vv = 0; vv < 5; ++vv)
        *(float2*)&w[vv * 4] = make_float2(rre[vv], rim[vv]);
}

__global__ __launch_bounds__(256) void stftA_kernel(const float* __restrict__ xin,
                                                    const float* __restrict__ xout,
                                                    float* __restrict__ R, int b0) {
    int t = blockIdx.x * 256 + threadIdx.x;
    if (t >= 6080) return;
    int c = blockIdx.y, bl = blockIdx.z;
    int bg = b0 + bl;
    int pc = t % 38, row = t / 38;
    float* RDb = R + (size_t)(bl * 3 + c) * BC_STRIDE;
    if (c == 0) { stftA_body<0>(xin, RDb, row, pc, bg, 0); stftA_body<0>(xout, RDb, row, pc, bg, 1); }
    else if (c == 1) { stftA_body<1>(xin, RDb, row, pc, bg, 0); stftA_body<1>(xout, RDb, row, pc, bg, 1); }
    else { stftA_body<2>(xin, RDb, row, pc, bg, 0); stftA_body<2>(xout, RDb, row, pc, bg, 1); }
}

// ---- stftB: stage one pc-slab (12.8 KB), column DFT + loss ----
__global__ __launch_bounds__(256) void stftB_kernel(const float* __restrict__ R,
                                                    float* __restrict__ partial, int b0) {
    __shared__ __align__(16) float S[160 * 20];   // [row][vv][img][2]
    __shared__ float TWT[60][2];                  // [uu*12+i] = {cos, -sin}

    int pc = blockIdx.x, c = blockIdx.y, bl = blockIdx.z;
    int tid = threadIdx.x;

    if (tid < 60) {
        int uu = tid / 12, i = tid % 12;
        float sn, cs;
        sincosf((float)((uu + 1) * i) * 0.5235987755982988f, &sn, &cs);
        TWT[tid][0] = cs; TWT[tid][1] = -sn;
    }
    const float* src = R + (size_t)(bl * 3 + c) * BC_STRIDE + pc * 20;
    for (int t = tid; t < 800; t += 256) {        // addr = 4t words: linear, conflict-free
        int row = t / 5, w = t % 5;
        *(float4*)&S[row * 20 + w * 4] = *(const float4*)&src[(size_t)row * 760 + w * 4];
    }
    __syncthreads();

    float acc = 0.f;
    if (tid < 190) {
        int uu = tid % 5;
        int pr = tid / 5;
        float FR0[5] = {0,0,0,0,0}, FI0[5] = {0,0,0,0,0};
        float FR1[5] = {0,0,0,0,0}, FI1[5] = {0,0,0,0,0};
        #pragma unroll
        for (int i = 0; i < 12; ++i) {
            float cu = TWT[uu * 12 + i][0], su = TWT[uu * 12 + i][1];
            const float4* q4 = (const float4*)&S[(4 * pr + i) * 20];
            #pragma unroll
            for (int vv = 0; vv < 5; ++vv) {
                float4 q = q4[vv];
                FR0[vv] += cu * q.x - su * q.y;   FI0[vv] += cu * q.y + su * q.x;
                FR1[vv] += cu * q.z - su * q.w;   FI1[vv] += cu * q.w + su * q.z;
            }
        }
        #pragma unroll
        for (int vv = 0; vv < 5; ++vv) {
            float aI = atan2f(FI0[vv], FR0[vv] + 1e-8f);
            float aO = atan2f(FI1[vv], FR1[vv] + 1e-8f);
            float mI = sqrtf(FR0[vv] * FR0[vv] + FI0[vv] * FI0[vv]);
            float mO = sqrtf(FR1[vv] * FR1[vv] + FI1[vv] * FI1[vv]);
            float ff = (float)((uu + 1) * (vv + 1)) * 0.04f;
            acc += ff * (fabsf(aO - aI) + fabsf(mO - mI));
        }
    }
    acc *= 1e-4f / 32.f;
    float s = block_sum<4>(acc);
    if (tid == 0)
        partial[H_TOTAL + pc + P * (c + 3 * (b0 + bl))] = s;
}

// ================= FALLBACK PATH (R4 kernels) =================

__global__ __launch_bounds__(320) void ssim_fb(const float* __restrict__ xin,
                                               const float* __restrict__ xout,
                                               float* __restrict__ partial) {
    __shared__ __align__(16) float sx[18 * 160];
    __shared__ __align__(16) float sy[18 * 160];
    __shared__ __align__(16) float V[5][8 * 160 + 16];

    const int tile = blockIdx.x, c = blockIdx.y, b = blockIdx.z;
    const int tid = threadIdx.x;
    const int r0 = tile * 8;
    {
        int col = tid % 160;
        int img = tid / 160;
        const float* src = img ? xout : xin;
        float* dst = img ? sy : sx;
        #pragma unroll
        for (int r = 0; r < 18; ++r) {
            int row = r0 + r;
            float v = 0.f;
            if (row < NPIX) v = src[(((size_t)b * NPIX + row) * NPIX + col) * CH + c];
            dst[r * 160 + col] = v;
        }
    }
    __syncthreads();
    {
        int orow = tid / 40;
        int cbase = (tid % 40) * 4;
        float ax[4] = {0,0,0,0}, ay[4] = {0,0,0,0};
        float axx[4] = {0,0,0,0}, ayy[4] = {0,0,0,0}, axy[4] = {0,0,0,0};
        #pragma unroll
        for (int k = 0; k < 11; ++k) {
            float4 qx = *(const float4*)&sx[(orow + k) * 160 + cbase];
            float4 qy = *(const float4*)&sy[(orow + k) * 160 + cbase];
            float w = GW[k];
            float xs[4] = {qx.x, qx.y, qx.z, qx.w};
            float ys[4] = {qy.x, qy.y, qy.z, qy.w};
            #pragma unroll
            for (int o = 0; o < 4; ++o) {
                ax[o]  += w * xs[o];          ay[o]  += w * ys[o];
                axx[o] += w * (xs[o]*xs[o]);  ayy[o] += w * (ys[o]*ys[o]);
                axy[o] += w * (xs[o]*ys[o]);
            }
        }
        int base = orow * 160 + cbase;
        *(float4*)&V[0][base] = make_float4(ax[0],  ax[1],  ax[2],  ax[3]);
        *(float4*)&V[1][base] = make_float4(ay[0],  ay[1],  ay[2],  ay[3]);
        *(float4*)&V[2][base] = make_float4(axx[0], axx[1], axx[2], axx[3]);
        *(float4*)&V[3][base] = make_float4(ayy[0], ayy[1], ayy[2], ayy[3]);
        *(float4*)&V[4][base] = make_float4(axy[0], axy[1], axy[2], axy[3]);
    }
    __syncthreads();
    float acc = 0.f;
    if (tid < 304) {
        int orow = tid / 38;
        int oc = (tid % 38) * 4;
        float st[5][4];
        #pragma unroll
        for (int p = 0; p < 5; ++p) {
            float vals[16];
            #pragma unroll
            for (int q = 0; q < 4; ++q) {
                float4 t4 = *(const float4*)&V[p][orow * 160 + oc + 4 * q];
                vals[4*q+0] = t4.x; vals[4*q+1] = t4.y; vals[4*q+2] = t4.z; vals[4*q+3] = t4.w;
            }
            #pragma unroll
            for (int o = 0; o < 4; ++o) {
                float s = 0.f;
                #pragma unroll
                for (int k = 0; k < 11; ++k) s += GW[k] * vals[o + k];
                st[p][o] = s;
            }
        }
        const float c1 = 1e-4f, c2 = 9e-4f;
        #pragma unroll
        for (int o = 0; o < 4; ++o) {
            if (r0 + orow < OUT_SZ && oc + o < OUT_SZ) {
                float mx = st[0][o], my = st[1][o];
                float vx = st[2][o] - mx * mx;
                float vy = st[3][o] - my * my;
                float cv = st[4][o] - mx * my;
                float lum = (2.f * mx * my + c1) / (mx * mx + my * my + c1);
                float cs  = (2.f * cv + c2) / (vx + vy + c2);
                acc += lum * cs;
            }
        }
    }
    acc *= 1.f / (32.f * 150.f * 150.f * 3.f);
    float s = block_sum<5>(acc);
    if (tid == 0) partial[blockIdx.x + SSIM_TILES * (blockIdx.y + CH * blockIdx.z)] = s;
}

__global__ __launch_bounds__(384) void stft_fb(const float* __restrict__ xin,
                                               const float* __restrict__ xout,
                                               float* __restrict__ partial) {
    __shared__ __align__(16) float rows[16 * RSTRIDE];
    __shared__ __align__(16) float RD[16 * 38 * 20];
    __shared__ float TWT[5][12][2];

    const int prg = blockIdx.x, c = blockIdx.y, b = blockIdx.z;
    const int tid = threadIdx.x;
    const int row0 = prg * 8;

    if (tid < 60) {
        int uu = tid / 12, i = tid % 12;
        float sn, cs;
        sincosf((float)((uu + 1) * i) * 0.5235987755982988f, &sn, &cs);
        TWT[uu][i][0] = cs; TWT[uu][i][1] = -sn;
    }
    for (int img = 0; img < 2; ++img) {
        const float* src = img ? xout : xin;
        for (int t = tid; t < 16 * 160; t += 384) {
            int r = t / 160, col = t % 160;
            rows[r * RSTRIDE + col] = src[(((size_t)b * NPIX + row0 + r) * NPIX + col) * CH + c];
        }
        __syncthreads();
        for (int t = tid; t < 608; t += 384) {
            int r = t & 15, pc = t >> 4;
            const float4* rp = (const float4*)&rows[r * RSTRIDE + pc * 4];
            float4 q0 = rp[0], q1 = rp[1], q2 = rp[2];
            float x[12] = {q0.x,q0.y,q0.z,q0.w, q1.x,q1.y,q1.z,q1.w, q2.x,q2.y,q2.z,q2.w};
            float rre[5] = {0,0,0,0,0}, rim[5] = {0,0,0,0,0};
            #pragma unroll
            for (int j = 0; j < 12; ++j) {
                #pragma unroll
                for (int vv = 0; vv < 5; ++vv) {
                    int k = ((vv + 1) * j) % 12;
                    rre[vv] += x[j] * TWC[k];
                    rim[vv] += x[j] * TWS[k];
                }
            }
            float* w = &RD[(r * 38 + pc) * 20 + img * 2];
            #pragma unroll
            for (int vv = 0; vv < 5; ++vv) {
                w[vv * 4 + 0] = rre[vv];
                w[vv * 4 + 1] = rim[vv];
            }
        }
        __syncthreads();
    }
    float acc = 0.f;
    if (tid < 380) {
        int uu = tid % 5;
        int rem = tid / 5;
        int pc = rem % 38;
        int g  = rem / 38;
        float FinR[5] = {0,0,0,0,0}, FinI[5] = {0,0,0,0,0};
        float FoutR[5] = {0,0,0,0,0}, FoutI[5] = {0,0,0,0,0};
        #pragma unroll
        for (int i = 0; i < 12; ++i) {
            float cu = TWT[uu][i][0], su = TWT[uu][i][1];
            const float4* q4 = (const float4*)&RD[((4 * g + i) * 38 + pc) * 20];
            #pragma unroll
            for (int vv = 0; vv < 5; ++vv) {
                float4 q = q4[vv];
                FinR[vv]  += cu * q.x - su * q.y;
                FinI[vv]  += cu * q.y + su * q.x;
                FoutR[vv] += cu * q.z - su * q.w;
                FoutI[vv] += cu * q.w + su * q.z;
            }
        }
        #pragma unroll
        for (int vv = 0; vv < 5; ++vv) {
            float aI = atan2f(FinI[vv],  FinR[vv]  + 1e-8f);
            float aO = atan2f(FoutI[vv], FoutR[vv] + 1e-8f);
            float mI = sqrtf(FinR[vv] * FinR[vv] + FinI[vv] * FinI[vv]);
            float mO = sqrtf(FoutR[vv] * FoutR[vv] + FoutI[vv] * FoutI[vv]);
            float ff = (float)((uu + 1) * (vv + 1)) * 0.04f;
            acc += ff * (fabsf(aO - aI) + fabsf(mO - mI));
        }
    }
    acc *= 1e-4f / 32.f;
    float s = block_sum<6>(acc);
    if (tid == 0)
        partial[FB_SSIM_BLOCKS + blockIdx.x + FB_STFT_PRG * (blockIdx.y + CH * blockIdx.z)] = s;
}

// ---------------- final reduce (+ KLD inline) ----------------
__global__ __launch_bounds__(1024) void final_kernel(const float* __restrict__ mean,
                                                     const float* __restrict__ logvar,
                                                     const float* __restrict__ partial,
                                                     int n, float* __restrict__ out) {
    float a = 0.f;
    for (int i = threadIdx.x; i < BATCH * LDIM; i += 1024) {
        float m = mean[i], lv = logvar[i];
        a += -0.5f * (1.f + lv - expf(lv) - m * m) * (1.f / 32.f);
    }
    for (int i = threadIdx.x; i < n; i += 1024) a += partial[i];
    float s = block_sum<16>(a);
    if (threadIdx.x == 0) out[0] = s;
}

extern "C" void kernel_launch(void* const* d_in, const int* in_sizes, int n_in,
                              void* d_out, int out_size, void* d_ws, size_t ws_size,
                              hipStream_t stream) {
    const float* mean   = (const float*)d_in[0];
    const float* logvar = (const float*)d_in[1];
    const float* xin    = (const float*)d_in[2];
    const float* xout   = (const float*)d_in[3];
    float* out = (float*)d_out;
    float* partial = (float*)d_ws;

    int CB = 0;
    for (int cand = 32; cand >= 1; cand >>= 1) {
        size_t need = (size_t)REGION_OFF + (size_t)cand * 3 * BC_STRIDE * 4;
        if (ws_size >= need) { CB = cand; break; }
    }
    if (CB) {
        float* R = (float*)((char*)d_ws + REGION_OFF);
        for (int b0 = 0; b0 < BATCH; b0 += CB) {
            ssimV_kernel<<<dim3(V_BLOCKS_PER_BC, 3, CB), 256, 0, stream>>>(xin, xout, R, b0);
            ssimH_kernel<<<dim3(H_BLOCKS_PER_BC, 3, CB), 256, 0, stream>>>(R, partial, b0);
            stftA_kernel<<<dim3(A_BLOCKS_PER_BC, 3, CB), 256, 0, stream>>>(xin, xout, R, b0);
            stftB_kernel<<<dim3(P, 3, CB), 256, 0, stream>>>(R, partial, b0);
        }
        final_kernel<<<1, 1024, 0, stream>>>(mean, logvar, partial, SPLIT_PARTIALS, out);
    } else {
        ssim_fb<<<dim3(SSIM_TILES, CH, BATCH), 320, 0, stream>>>(xin, xout, partial);
        stft_fb<<<dim3(FB_STFT_PRG, CH, BATCH), 384, 0, stream>>>(xin, xout, partial);
        final_kernel<<<1, 1024, 0, stream>>>(mean, logvar, partial, FB_PARTIALS, out);
    }
}

// Round 6
// 152.784 us; speedup vs baseline: 1.5169x; 1.5169x over previous
//
#include <hip/hip_runtime.h>
#include <math.h>

#define BATCH 32
#define NPIX 160
#define CH 3
#define LDIM 128
#define OUT_SZ 150        // 160 - 11 + 1
#define P 38              // (160-12)/4 + 1
#define PLANE 25600       // 160*160

#define SSIM_TILES 19
#define SSIM_BLOCKS (SSIM_TILES*CH*BATCH)    // 1824
#define STFT_PRG 19                          // 2 patch-rows per block
#define STFT_BLOCKS (STFT_PRG*CH*BATCH)      // 1824
#define TOTAL_PARTIALS (SSIM_BLOCKS + STFT_BLOCKS)
#define PLANES_OFF 32768                     // bytes: partials live below this

// e^{-i*2pi*k/12} (folds at compile time in unrolled loops)
__device__ constexpr float TWC[12] = { 1.f, 0.86602540f, 0.5f, 0.f, -0.5f, -0.86602540f,
                                      -1.f,-0.86602540f,-0.5f, 0.f,  0.5f,  0.86602540f};
__device__ constexpr float TWS[12] = { 0.f,-0.5f,-0.86602540f,-1.f,-0.86602540f,-0.5f,
                                       0.f, 0.5f, 0.86602540f, 1.f, 0.86602540f, 0.5f};

// normalized gaussian(11, sigma=1.5)
__device__ constexpr float GW[11] = {0.00102838f, 0.00759876f, 0.03600076f, 0.10936070f,
                                     0.21300554f, 0.26601172f, 0.21300554f, 0.10936070f,
                                     0.03600076f, 0.00759876f, 0.00102838f};

template<int NWAVES>
__device__ __forceinline__ float block_sum(float v) {
    #pragma unroll
    for (int o = 32; o > 0; o >>= 1) v += __shfl_down(v, o, 64);
    __shared__ float sm[NWAVES];
    int w = threadIdx.x >> 6;
    if ((threadIdx.x & 63) == 0) sm[w] = v;
    __syncthreads();
    if (threadIdx.x == 0) {
        v = sm[0];
        #pragma unroll
        for (int i = 1; i < NWAVES; ++i) v += sm[i];
    }
    return v;
}

// ---------------- transpose: NHWC -> planar [img][b][c][row][col] ----------------
// thread = (img, b, row, colq): 3 float4 reads (12 interleaved floats = 4 pixels x 3ch),
// 3 float4 plane writes. All aligned, all coalesced. 409600 threads = 1600 blocks.
__global__ __launch_bounds__(256) void transpose_kernel(const float* __restrict__ xin,
                                                        const float* __restrict__ xout,
                                                        float* __restrict__ Pl) {
    int t = blockIdx.x * 256 + threadIdx.x;
    int colq = t % 40;
    int row  = (t / 40) % 160;
    int b    = (t / 6400) % 32;
    int img  = t / 204800;
    const float* src = img ? xout : xin;
    const float4* q = (const float4*)(src + ((size_t)(b * 160 + row) * 160 + colq * 4) * 3);
    float4 f0 = q[0], f1 = q[1], f2 = q[2];
    float* dst = Pl + (size_t)(img * 96 + b * 3) * PLANE + row * 160 + colq * 4;
    *(float4*)(dst)             = make_float4(f0.x, f0.w, f1.z, f2.y);   // ch0
    *(float4*)(dst + PLANE)     = make_float4(f0.y, f1.x, f1.w, f2.z);   // ch1
    *(float4*)(dst + 2 * PLANE) = make_float4(f0.z, f1.y, f2.x, f2.w);   // ch2
}

// ---------------- SSIM (planar) ----------------
// block = (tile of 8 output rows, c, b), 320 threads. LDS = only V planes (25.9 KB).
// phase2: vertical 11-tap reading planar global directly (L1-served, 11x reuse);
// phase3: horizontal 11-tap from LDS + SSIM formula + reduce.
__global__ __launch_bounds__(320) void ssim_kernel(const float* __restrict__ Pl,
                                                   float* __restrict__ partial) {
    __shared__ __align__(16) float V[5][8 * 160 + 16];

    const int tile = blockIdx.x, c = blockIdx.y, b = blockIdx.z;
    const int tid = threadIdx.x;
    const int r0 = tile * 8;
    const float* px = Pl + (size_t)(b * 3 + c) * PLANE;
    const float* py = px + (size_t)96 * PLANE;

    // phase 2: thread = (orow, colq): 8*40 = 320 tasks exactly
    {
        int orow = tid / 40;
        int cbase = (tid % 40) * 4;
        float ax[4] = {0,0,0,0}, ay[4] = {0,0,0,0};
        float axx[4] = {0,0,0,0}, ayy[4] = {0,0,0,0}, axy[4] = {0,0,0,0};
        #pragma unroll
        for (int k = 0; k < 11; ++k) {
            int row = r0 + orow + k;
            row = row < 160 ? row : 159;          // clamp; clamped rows unused by phase 3
            float4 qx = *(const float4*)(px + row * 160 + cbase);
            float4 qy = *(const float4*)(py + row * 160 + cbase);
            float w = GW[k];
            float xs[4] = {qx.x, qx.y, qx.z, qx.w};
            float ys[4] = {qy.x, qy.y, qy.z, qy.w};
            #pragma unroll
            for (int o = 0; o < 4; ++o) {
                ax[o]  += w * xs[o];          ay[o]  += w * ys[o];
                axx[o] += w * (xs[o]*xs[o]);  ayy[o] += w * (ys[o]*ys[o]);
                axy[o] += w * (xs[o]*ys[o]);
            }
        }
        int base = orow * 160 + cbase;
        *(float4*)&V[0][base] = make_float4(ax[0],  ax[1],  ax[2],  ax[3]);
        *(float4*)&V[1][base] = make_float4(ay[0],  ay[1],  ay[2],  ay[3]);
        *(float4*)&V[2][base] = make_float4(axx[0], axx[1], axx[2], axx[3]);
        *(float4*)&V[3][base] = make_float4(ayy[0], ayy[1], ayy[2], ayy[3]);
        *(float4*)&V[4][base] = make_float4(axy[0], axy[1], axy[2], axy[3]);
    }
    __syncthreads();

    // phase 3: 8 rows * 38 col-quads = 304 tasks
    float acc = 0.f;
    if (tid < 304) {
        int orow = tid / 38;
        int oc = (tid % 38) * 4;
        float st[5][4];
        #pragma unroll
        for (int p = 0; p < 5; ++p) {
            float vals[16];
            #pragma unroll
            for (int q = 0; q < 4; ++q) {
                float4 t4 = *(const float4*)&V[p][orow * 160 + oc + 4 * q];
                vals[4*q+0] = t4.x; vals[4*q+1] = t4.y; vals[4*q+2] = t4.z; vals[4*q+3] = t4.w;
            }
            #pragma unroll
            for (int o = 0; o < 4; ++o) {
                float s = 0.f;
                #pragma unroll
                for (int k = 0; k < 11; ++k) s += GW[k] * vals[o + k];
                st[p][o] = s;
            }
        }
        const float c1 = 1e-4f, c2 = 9e-4f;
        #pragma unroll
        for (int o = 0; o < 4; ++o) {
            if (r0 + orow < OUT_SZ && oc + o < OUT_SZ) {
                float mx = st[0][o], my = st[1][o];
                float vx = st[2][o] - mx * mx;
                float vy = st[3][o] - my * my;
                float cv = st[4][o] - mx * my;
                float lum = (2.f * mx * my + c1) / (mx * mx + my * my + c1);
                float cs  = (2.f * cv + c2) / (vx + vy + c2);
                acc += lum * cs;
            }
        }
    }
    acc *= 1.f / (32.f * 150.f * 150.f * 3.f);
    float s = block_sum<5>(acc);
    if (tid == 0) partial[blockIdx.x + SSIM_TILES * (blockIdx.y + CH * blockIdx.z)] = s;
}

// ---------------- STFT (planar, fused) ----------------
// block = (prg, c, b), 512 threads; covers pr = {2*prg, 2*prg+1}, rows 8*prg..+15.
// Phase A: row DFT per (img, r, pc) reading planar global directly (L1 reuse).
// RD layout [r][vv][img][pc][2]: ALL LDS accesses are lane-contiguous b64 ->
// conflict-free. Phase B: 1900 tasks (g, uv, pc), 4 accumulators each.
__global__ __launch_bounds__(512) void stft_kernel(const float* __restrict__ Pl,
                                                   float* __restrict__ partial) {
    __shared__ __align__(16) float RD[16 * 5 * 2 * 38 * 2];  // 12160 floats = 48.6 KB
    __shared__ float TWT[60][2];                             // e^{-i*2pi*u*i/12}

    const int prg = blockIdx.x, c = blockIdx.y, b = blockIdx.z;
    const int tid = threadIdx.x;
    const int row0 = prg * 8;
    const float* base0 = Pl + (size_t)(b * 3 + c) * PLANE;          // xin plane
    const float* base1 = base0 + (size_t)96 * PLANE;                // xout plane

    if (tid < 60) {
        int uu = tid / 12, i = tid % 12;
        float sn, cs;
        sincosf((float)((uu + 1) * i) * 0.5235987755982988f, &sn, &cs);
        TWT[tid][0] = cs; TWT[tid][1] = -sn;
    }

    // phase A: 2img * 16r * 38pc = 1216 row-DFT tasks
    for (int t = tid; t < 1216; t += 512) {
        int pc = t % 38;
        int r  = (t / 38) % 16;
        int img = t / 608;
        const float* rp = (img ? base1 : base0) + (row0 + r) * 160 + pc * 4;
        float4 q0 = *(const float4*)(rp);
        float4 q1 = *(const float4*)(rp + 4);
        float4 q2 = *(const float4*)(rp + 8);
        float x[12] = {q0.x,q0.y,q0.z,q0.w, q1.x,q1.y,q1.z,q1.w, q2.x,q2.y,q2.z,q2.w};
        float rre[5] = {0,0,0,0,0}, rim[5] = {0,0,0,0,0};
        #pragma unroll
        for (int j = 0; j < 12; ++j) {
            #pragma unroll
            for (int vv = 0; vv < 5; ++vv) {
                int k = ((vv + 1) * j) % 12;   // compile-time
                rre[vv] += x[j] * TWC[k];
                rim[vv] += x[j] * TWS[k];
            }
        }
        #pragma unroll
        for (int vv = 0; vv < 5; ++vv) {
            int idx = (((r * 5 + vv) * 2 + img) * 38 + pc) * 2;
            *(float2*)&RD[idx] = make_float2(rre[vv], rim[vv]);
        }
    }
    __syncthreads();

    // phase B: (g, uv, pc) = 2*25*38 = 1900 tasks; column DFT + loss
    float acc = 0.f;
    for (int t = tid; t < 1900; t += 512) {
        int pc = t % 38;
        int uv = (t / 38) % 25;
        int g  = t / 950;
        int uu = uv / 5, vv = uv % 5;
        float FR0 = 0.f, FI0 = 0.f, FR1 = 0.f, FI1 = 0.f;
        #pragma unroll
        for (int i = 0; i < 12; ++i) {
            float cu = TWT[uu * 12 + i][0], su = TWT[uu * 12 + i][1];
            int r = 4 * g + i;
            float2 a  = *(const float2*)&RD[(((r * 5 + vv) * 2 + 0) * 38 + pc) * 2];
            float2 bb = *(const float2*)&RD[(((r * 5 + vv) * 2 + 1) * 38 + pc) * 2];
            FR0 += cu * a.x  - su * a.y;   FI0 += cu * a.y  + su * a.x;
            FR1 += cu * bb.x - su * bb.y;  FI1 += cu * bb.y + su * bb.x;
        }
        float aI = atan2f(FI0, FR0 + 1e-8f);
        float aO = atan2f(FI1, FR1 + 1e-8f);
        float mI = sqrtf(FR0 * FR0 + FI0 * FI0);
        float mO = sqrtf(FR1 * FR1 + FI1 * FI1);
        float ff = (float)((uu + 1) * (vv + 1)) * 0.04f;
        acc += ff * (fabsf(aO - aI) + fabsf(mO - mI));
    }
    acc *= 1e-4f / 32.f;
    float s = block_sum<8>(acc);
    if (tid == 0)
        partial[SSIM_BLOCKS + blockIdx.x + STFT_PRG * (blockIdx.y + CH * blockIdx.z)] = s;
}

// ---------------- final reduce (+ KLD inline) ----------------
__global__ __launch_bounds__(1024) void final_kernel(const float* __restrict__ mean,
                                                     const float* __restrict__ logvar,
                                                     const float* __restrict__ partial,
                                                     float* __restrict__ out) {
    float a = 0.f;
    for (int i = threadIdx.x; i < BATCH * LDIM; i += 1024) {
        float m = mean[i], lv = logvar[i];
        a += -0.5f * (1.f + lv - expf(lv) - m * m) * (1.f / 32.f);
    }
    for (int i = threadIdx.x; i < TOTAL_PARTIALS; i += 1024) a += partial[i];
    float s = block_sum<16>(a);
    if (threadIdx.x == 0) out[0] = s;
}

extern "C" void kernel_launch(void* const* d_in, const int* in_sizes, int n_in,
                              void* d_out, int out_size, void* d_ws, size_t ws_size,
                              hipStream_t stream) {
    const float* mean   = (const float*)d_in[0];
    const float* logvar = (const float*)d_in[1];
    const float* xin    = (const float*)d_in[2];
    const float* xout   = (const float*)d_in[3];
    float* out = (float*)d_out;
    float* partial = (float*)d_ws;
    float* Pl = (float*)((char*)d_ws + PLANES_OFF);   // 19.7 MB planes; ws >= 46.7 MB (proven R5)

    transpose_kernel<<<1600, 256, 0, stream>>>(xin, xout, Pl);
    ssim_kernel<<<dim3(SSIM_TILES, CH, BATCH), 320, 0, stream>>>(Pl, partial);
    stft_kernel<<<dim3(STFT_PRG, CH, BATCH), 512, 0, stream>>>(Pl, partial);
    final_kernel<<<1, 1024, 0, stream>>>(mean, logvar, partial, out);
}

// Round 7
// 142.244 us; speedup vs baseline: 1.6292x; 1.0741x over previous
//
#include <hip/hip_runtime.h>
#include <math.h>

#define BATCH 32
#define NPIX 160
#define CH 3
#define LDIM 128
#define OUT_SZ 150        // 160 - 11 + 1
#define P 38              // (160-12)/4 + 1
#define PLANE 25600       // 160*160

#define STFT_PRG 19                           // 2 patch-rows per stft block
#define N_STFT (STFT_PRG*CH*BATCH)            // 1824
#define SSIM_TILES 10                         // 16 output rows per tile
#define N_SSIM (SSIM_TILES*CH*BATCH)          // 960
#define N_BLOCKS (N_STFT + N_SSIM)            // 2784 = 32 groups of (57 stft + 30 ssim)
#define TOTAL_PARTIALS N_BLOCKS
#define PLANES_OFF 32768

// e^{-i*2pi*k/12}; entries are 0 / ±0.5 / ±0.866 / ±1 -> many FMAs fold away
__device__ constexpr float TWC[12] = { 1.f, 0.86602540f, 0.5f, 0.f, -0.5f, -0.86602540f,
                                      -1.f,-0.86602540f,-0.5f, 0.f,  0.5f,  0.86602540f};
__device__ constexpr float TWS[12] = { 0.f,-0.5f,-0.86602540f,-1.f,-0.86602540f,-0.5f,
                                       0.f, 0.5f, 0.86602540f, 1.f, 0.86602540f, 0.5f};

// normalized gaussian(11, sigma=1.5)
__device__ constexpr float GW[11] = {0.00102838f, 0.00759876f, 0.03600076f, 0.10936070f,
                                     0.21300554f, 0.26601172f, 0.21300554f, 0.10936070f,
                                     0.03600076f, 0.00759876f, 0.00102838f};

// minimax atan poly on [0,1], max err ~1e-6 rad
__device__ __forceinline__ float fast_atan2f(float y, float x) {
    float ax = fabsf(x), ay = fabsf(y);
    float mx = fmaxf(ax, ay), mn = fminf(ax, ay);
    float z = mn / mx;
    float z2 = z * z;
    float p = fmaf(z2, -0.01172120f, 0.05265332f);
    p = fmaf(z2, p, -0.11643287f);
    p = fmaf(z2, p, 0.19354346f);
    p = fmaf(z2, p, -0.33262347f);
    p = fmaf(z2, p, 0.99997726f);
    p = p * z;
    if (ay > ax) p = 1.57079632679489662f - p;
    if (x < 0.f) p = 3.14159265358979323f - p;
    return (y < 0.f) ? -p : p;
}

// ---------------- transpose: NHWC -> planar [img][b][c][row][col] ----------------
__global__ __launch_bounds__(256) void transpose_kernel(const float* __restrict__ xin,
                                                        const float* __restrict__ xout,
                                                        float* __restrict__ Pl) {
    int t = blockIdx.x * 256 + threadIdx.x;
    int colq = t % 40;
    int row  = (t / 40) % 160;
    int b    = (t / 6400) % 32;
    int img  = t / 204800;
    const float* src = img ? xout : xin;
    const float4* q = (const float4*)(src + ((size_t)(b * 160 + row) * 160 + colq * 4) * 3);
    float4 f0 = q[0], f1 = q[1], f2 = q[2];
    float* dst = Pl + (size_t)(img * 96 + b * 3) * PLANE + row * 160 + colq * 4;
    *(float4*)(dst)             = make_float4(f0.x, f0.w, f1.z, f2.y);
    *(float4*)(dst + PLANE)     = make_float4(f0.y, f1.x, f1.w, f2.z);
    *(float4*)(dst + 2 * PLANE) = make_float4(f0.z, f1.y, f2.x, f2.w);
}

// ---------------- fused ssim + stft, block-role specialized ----------------
// SMEM carved per role: stft RD = 12160 floats ([r][vv][img][pc][2]);
// ssim V planes = 5 x (16*160+16) = 12880 floats.
__global__ __launch_bounds__(512) void fused_kernel(const float* __restrict__ Pl,
                                                    float* __restrict__ partial) {
    __shared__ __align__(16) float SMEM[12880];
    __shared__ float sm8[8];

    const int tid = threadIdx.x;
    const int gid = blockIdx.x;
    const int grp = gid / 87, k87 = gid % 87;
    const bool is_stft = (k87 < 57);
    float acc = 0.f;
    int pslot;

    if (is_stft) {
        // ---------------- STFT role ----------------
        int idx = grp * 57 + k87;                 // 0..1823
        pslot = idx;
        int prg = idx % 19;
        int c   = (idx / 19) % 3;
        int b   = idx / 57;
        int row0 = prg * 8;
        const float* base0 = Pl + (size_t)(b * 3 + c) * PLANE;
        const float* base1 = base0 + (size_t)96 * PLANE;
        float* RD = SMEM;

        // phase A: 1216 row-DFT tasks, real-input symmetry (~4x fewer ops)
        for (int t = tid; t < 1216; t += 512) {
            int pc = t % 38;
            int r  = (t / 38) % 16;
            int img = t / 608;
            const float* rp = (img ? base1 : base0) + (row0 + r) * 160 + pc * 4;
            float4 q0 = *(const float4*)(rp);
            float4 q1 = *(const float4*)(rp + 4);
            float4 q2 = *(const float4*)(rp + 8);
            float x[12] = {q0.x,q0.y,q0.z,q0.w, q1.x,q1.y,q1.z,q1.w, q2.x,q2.y,q2.z,q2.w};
            float e1 = x[1] + x[11], o1 = x[1] - x[11];
            float e2 = x[2] + x[10], o2 = x[2] - x[10];
            float e3 = x[3] + x[9],  o3 = x[3] - x[9];
            float e4 = x[4] + x[8],  o4 = x[4] - x[8];
            float e5 = x[5] + x[7],  o5 = x[5] - x[7];
            float ev[5] = {e1, e2, e3, e4, e5};
            float ov[5] = {o1, o2, o3, o4, o5};
            #pragma unroll
            for (int vv = 0; vv < 5; ++vv) {
                int v = vv + 1;
                float re = x[0] + ((v & 1) ? -x[6] : x[6]);
                float im = 0.f;
                #pragma unroll
                for (int j = 1; j <= 5; ++j) {
                    int kk = (v * j) % 12;         // compile-time; 0/±1/±.5 coefs fold
                    re = fmaf(ev[j-1], TWC[kk], re);
                    im = fmaf(ov[j-1], TWS[kk], im);
                }
                int idx2 = (((r * 5 + vv) * 2 + img) * 38 + pc) * 2;
                *(float2*)&RD[idx2] = make_float2(re, im);
            }
        }
        __syncthreads();

        // phase B: 380 tasks (g, vv, pc); half-period fold, all 5 u per task
        if (tid < 380) {
            int pc = tid % 38;
            int vv = (tid / 38) % 5;
            int g  = tid / 190;
            float FR0[5] = {0,0,0,0,0}, FI0[5] = {0,0,0,0,0};
            float FR1[5] = {0,0,0,0,0}, FI1[5] = {0,0,0,0,0};
            #pragma unroll
            for (int i = 0; i < 6; ++i) {
                int rlo = 4 * g + i, rhi = rlo + 6;
                float2 a0 = *(const float2*)&SMEM[(((rlo * 5 + vv) * 2 + 0) * 38 + pc) * 2];
                float2 a6 = *(const float2*)&SMEM[(((rhi * 5 + vv) * 2 + 0) * 38 + pc) * 2];
                float2 b0 = *(const float2*)&SMEM[(((rlo * 5 + vv) * 2 + 1) * 38 + pc) * 2];
                float2 b6 = *(const float2*)&SMEM[(((rhi * 5 + vv) * 2 + 1) * 38 + pc) * 2];
                float spR0 = a0.x + a6.x, spI0 = a0.y + a6.y;
                float smR0 = a0.x - a6.x, smI0 = a0.y - a6.y;
                float spR1 = b0.x + b6.x, spI1 = b0.y + b6.y;
                float smR1 = b0.x - b6.x, smI1 = b0.y - b6.y;
                #pragma unroll
                for (int uu = 0; uu < 5; ++uu) {
                    int u = uu + 1;
                    int kk = (u * i) % 12;         // compile-time twiddle
                    float cu = TWC[kk], su = TWS[kk];
                    float sR0 = (u & 1) ? smR0 : spR0, sI0 = (u & 1) ? smI0 : spI0;
                    float sR1 = (u & 1) ? smR1 : spR1, sI1 = (u & 1) ? smI1 : spI1;
                    FR0[uu] = fmaf(cu, sR0, fmaf(-su, sI0, FR0[uu]));
                    FI0[uu] = fmaf(cu, sI0, fmaf( su, sR0, FI0[uu]));
                    FR1[uu] = fmaf(cu, sR1, fmaf(-su, sI1, FR1[uu]));
                    FI1[uu] = fmaf(cu, sI1, fmaf( su, sR1, FI1[uu]));
                }
            }
            #pragma unroll
            for (int uu = 0; uu < 5; ++uu) {
                float aI = fast_atan2f(FI0[uu], FR0[uu] + 1e-8f);
                float aO = fast_atan2f(FI1[uu], FR1[uu] + 1e-8f);
                float mI = sqrtf(FR0[uu] * FR0[uu] + FI0[uu] * FI0[uu]);
                float mO = sqrtf(FR1[uu] * FR1[uu] + FI1[uu] * FI1[uu]);
                float ff = (float)((uu + 1) * (vv + 1)) * 0.04f;
                acc += ff * (fabsf(aO - aI) + fabsf(mO - mI));
            }
        }
        acc *= 1e-4f / 32.f;
    } else {
        // ---------------- SSIM role ----------------
        int idx = grp * 30 + (k87 - 57);          // 0..959
        pslot = N_STFT + idx;
        int tile = idx % 10;
        int c    = (idx / 10) % 3;
        int b    = idx / 30;
        int r0 = tile * 16;
        const float* px = Pl + (size_t)(b * 3 + c) * PLANE;
        const float* py = px + (size_t)96 * PLANE;

        // phase 2: vertical 11-tap, 16*40 = 640 tasks
        for (int t = tid; t < 640; t += 512) {
            int orow = t / 40;
            int cbase = (t % 40) * 4;
            float ax[4] = {0,0,0,0}, ay[4] = {0,0,0,0};
            float axx[4] = {0,0,0,0}, ayy[4] = {0,0,0,0}, axy[4] = {0,0,0,0};
            #pragma unroll
            for (int kk = 0; kk < 11; ++kk) {
                int row = r0 + orow + kk;
                row = row < 160 ? row : 159;      // clamped rows feed only masked outputs
                float4 qx = *(const float4*)(px + row * 160 + cbase);
                float4 qy = *(const float4*)(py + row * 160 + cbase);
                float w = GW[kk];
                float xs[4] = {qx.x, qx.y, qx.z, qx.w};
                float ys[4] = {qy.x, qy.y, qy.z, qy.w};
                #pragma unroll
                for (int o = 0; o < 4; ++o) {
                    ax[o]  += w * xs[o];          ay[o]  += w * ys[o];
                    axx[o] += w * (xs[o]*xs[o]);  ayy[o] += w * (ys[o]*ys[o]);
                    axy[o] += w * (xs[o]*ys[o]);
                }
            }
            int base = orow * 160 + cbase;
            *(float4*)&SMEM[0 * 2576 + base] = make_float4(ax[0],  ax[1],  ax[2],  ax[3]);
            *(float4*)&SMEM[1 * 2576 + base] = make_float4(ay[0],  ay[1],  ay[2],  ay[3]);
            *(float4*)&SMEM[2 * 2576 + base] = make_float4(axx[0], axx[1], axx[2], axx[3]);
            *(float4*)&SMEM[3 * 2576 + base] = make_float4(ayy[0], ayy[1], ayy[2], ayy[3]);
            *(float4*)&SMEM[4 * 2576 + base] = make_float4(axy[0], axy[1], axy[2], axy[3]);
        }
        __syncthreads();

        // phase 3: horizontal 11-tap + SSIM, 16*38 = 608 tasks
        for (int t = tid; t < 608; t += 512) {
            int orow = t / 38;
            int oc = (t % 38) * 4;
            float st[5][4];
            #pragma unroll
            for (int p = 0; p < 5; ++p) {
                float vals[16];
                #pragma unroll
                for (int q = 0; q < 4; ++q) {
                    float4 t4 = *(const float4*)&SMEM[p * 2576 + orow * 160 + oc + 4 * q];
                    vals[4*q+0] = t4.x; vals[4*q+1] = t4.y; vals[4*q+2] = t4.z; vals[4*q+3] = t4.w;
                }
                #pragma unroll
                for (int o = 0; o < 4; ++o) {
                    float s = 0.f;
                    #pragma unroll
                    for (int kk = 0; kk < 11; ++kk) s += GW[kk] * vals[o + kk];
                    st[p][o] = s;
                }
            }
            const float c1 = 1e-4f, c2 = 9e-4f;
            #pragma unroll
            for (int o = 0; o < 4; ++o) {
                if (r0 + orow < OUT_SZ && oc + o < OUT_SZ) {
                    float mx = st[0][o], my = st[1][o];
                    float vx = st[2][o] - mx * mx;
                    float vy = st[3][o] - my * my;
                    float cv = st[4][o] - mx * my;
                    float lum = (2.f * mx * my + c1) / (mx * mx + my * my + c1);
                    float cs  = (2.f * cv + c2) / (vx + vy + c2);
                    acc += lum * cs;
                }
            }
        }
        acc *= 1.f / (32.f * 150.f * 150.f * 3.f);
    }

    // block reduction (8 waves) into one partial
    #pragma unroll
    for (int o = 32; o > 0; o >>= 1) acc += __shfl_down(acc, o, 64);
    int w = tid >> 6;
    __syncthreads();
    if ((tid & 63) == 0) sm8[w] = acc;
    __syncthreads();
    if (tid == 0) {
        float s = sm8[0];
        #pragma unroll
        for (int i = 1; i < 8; ++i) s += sm8[i];
        partial[pslot] = s;
    }
}

// ---------------- final reduce (+ KLD inline) ----------------
__global__ __launch_bounds__(1024) void final_kernel(const float* __restrict__ mean,
                                                     const float* __restrict__ logvar,
                                                     const float* __restrict__ partial,
                                                     float* __restrict__ out) {
    float a = 0.f;
    for (int i = threadIdx.x; i < BATCH * LDIM; i += 1024) {
        float m = mean[i], lv = logvar[i];
        a += -0.5f * (1.f + lv - expf(lv) - m * m) * (1.f / 32.f);
    }
    for (int i = threadIdx.x; i < TOTAL_PARTIALS; i += 1024) a += partial[i];
    #pragma unroll
    for (int o = 32; o > 0; o >>= 1) a += __shfl_down(a, o, 64);
    __shared__ float sm[16];
    int w = threadIdx.x >> 6;
    if ((threadIdx.x & 63) == 0) sm[w] = a;
    __syncthreads();
    if (threadIdx.x == 0) {
        float s = sm[0];
        #pragma unroll
        for (int i = 1; i < 16; ++i) s += sm[i];
        out[0] = s;
    }
}

extern "C" void kernel_launch(void* const* d_in, const int* in_sizes, int n_in,
                              void* d_out, int out_size, void* d_ws, size_t ws_size,
                              hipStream_t stream) {
    const float* mean   = (const float*)d_in[0];
    const float* logvar = (const float*)d_in[1];
    const float* xin    = (const float*)d_in[2];
    const float* xout   = (const float*)d_in[3];
    float* out = (float*)d_out;
    float* partial = (float*)d_ws;
    float* Pl = (float*)((char*)d_ws + PLANES_OFF);   // 19.7 MB planes (ws proven >= 46.7 MB)

    transpose_kernel<<<1600, 256, 0, stream>>>(xin, xout, Pl);
    fused_kernel<<<N_BLOCKS, 512, 0, stream>>>(Pl, partial);
    final_kernel<<<1, 1024, 0, stream>>>(mean, logvar, partial, out);
}